// Round 1
// baseline (362.027 us; speedup 1.0000x reference)
//
#include <hip/hip_runtime.h>
#include <hip/hip_bf16.h>

typedef short bf16x8 __attribute__((ext_vector_type(8)));
typedef float f32x4  __attribute__((ext_vector_type(4)));

typedef __attribute__((address_space(3))) void lds_t;
typedef __attribute__((address_space(1))) void gbl_t;

#define MFMA16(a,b,c) __builtin_amdgcn_mfma_f32_16x16x32_bf16((a),(b),(c),0,0,0)

__device__ __forceinline__ unsigned short f2bf(float f) {
    __hip_bfloat16 h = __float2bfloat16(f);
    return __builtin_bit_cast(unsigned short, h);
}
__device__ __forceinline__ float bf2f(unsigned short u) {
    __hip_bfloat16 h = __builtin_bit_cast(__hip_bfloat16, u);
    return __bfloat162float(h);
}

// Split f32 rows [R][1024] -> dst [R][2048] = [hi | lo] bf16
__global__ void prep_split_rows(const float* __restrict__ src,
                                unsigned short* __restrict__ dst, int total) {
    for (int idx = blockIdx.x * blockDim.x + threadIdx.x; idx < total;
         idx += gridDim.x * blockDim.x) {
        int m = idx >> 10, c = idx & 1023;
        float v = src[idx];
        unsigned short hi = f2bf(v);
        float r = v - bf2f(hi);
        dst[(size_t)m * 2048 + c] = hi;
        dst[(size_t)m * 2048 + 1024 + c] = f2bf(r);
    }
}

// w_qkv [3072][1024] with einops row permute: output row n = which*1024 + h*64 + d
// reads source row d*48 + which*16 + h.  dst [3072][2048] = [hi | lo]
__global__ void prep_split_wqkv(const float* __restrict__ w,
                                unsigned short* __restrict__ dst) {
    for (int idx = blockIdx.x * blockDim.x + threadIdx.x; idx < 3072 * 1024;
         idx += gridDim.x * blockDim.x) {
        int n = idx >> 10, c = idx & 1023;
        int d = n & 63, which = n >> 10, h = (n >> 6) & 15;
        int srow = d * 48 + which * 16 + h;
        float v = w[(size_t)srow * 1024 + c];
        unsigned short hi = f2bf(v);
        float r = v - bf2f(hi);
        dst[(size_t)n * 2048 + c] = hi;
        dst[(size_t)n * 2048 + 1024 + c] = f2bf(r);
    }
}

// Split GEMM, virtual K = 3072 over A=[hi|hi|lo], B=[hi|lo|hi] (each stored [rows][2048]).
// C[m,n] = sum_k A[m,k]*B[n,k].  128x128 tile, BK=32, 4 waves (2x2), wave tile 64x64.
// MODE 0: scatter bf16 into q/k/v [bh][t][64].  MODE 1: f32 out [M][N].
template <int MODE>
__global__ __launch_bounds__(256) void gemm_split(
    const unsigned short* __restrict__ A, const unsigned short* __restrict__ B,
    float* __restrict__ outF, unsigned short* __restrict__ outQ,
    unsigned short* __restrict__ outK, unsigned short* __restrict__ outV, int N) {
    __shared__ unsigned short As[128 * 32];
    __shared__ unsigned short Bs[128 * 32];
    const int tid = threadIdx.x;
    const int w = tid >> 6, lane = tid & 63;
    const int lrow = lane & 15, lgrp = lane >> 4;
    const int wrow = w >> 1, wcol = w & 1;
    const int mtile = blockIdx.y * 128, ntile = blockIdx.x * 128;

    f32x4 acc[4][4];
#pragma unroll
    for (int i = 0; i < 4; i++)
#pragma unroll
        for (int j = 0; j < 4; j++) {
            f32x4 z = {0.f, 0.f, 0.f, 0.f};
            acc[i][j] = z;
        }

    const int srow = w * 32 + (lane >> 2);  // + i*16
    const int scol = (lane & 3) * 8;

    for (int ks = 0; ks < 96; ++ks) {
        const int kb = ks * 32;
        const int ac = (kb < 1024) ? kb : kb - 1024;
        const int bc = (kb < 2048) ? kb : kb - 2048;
        __syncthreads();
#pragma unroll
        for (int i = 0; i < 2; ++i) {
            const unsigned short* ga =
                A + (size_t)(mtile + srow + i * 16) * 2048 + ac + scol;
            __builtin_amdgcn_global_load_lds((const gbl_t*)ga,
                                             (lds_t*)(As + w * 1024 + i * 512),
                                             16, 0, 0);
        }
#pragma unroll
        for (int i = 0; i < 2; ++i) {
            const unsigned short* gb =
                B + (size_t)(ntile + srow + i * 16) * 2048 + bc + scol;
            __builtin_amdgcn_global_load_lds((const gbl_t*)gb,
                                             (lds_t*)(Bs + w * 1024 + i * 512),
                                             16, 0, 0);
        }
        asm volatile("s_waitcnt vmcnt(0)" ::: "memory");
        __syncthreads();

        bf16x8 af[4], bfv[4];
#pragma unroll
        for (int i = 0; i < 4; i++)
            af[i] = *reinterpret_cast<const bf16x8*>(
                As + (wrow * 64 + i * 16 + lrow) * 32 + lgrp * 8);
#pragma unroll
        for (int j = 0; j < 4; j++)
            bfv[j] = *reinterpret_cast<const bf16x8*>(
                Bs + (wcol * 64 + j * 16 + lrow) * 32 + lgrp * 8);
#pragma unroll
        for (int i = 0; i < 4; i++)
#pragma unroll
            for (int j = 0; j < 4; j++)
                acc[i][j] = MFMA16(af[i], bfv[j], acc[i][j]);
    }

#pragma unroll
    for (int i = 0; i < 4; i++) {
#pragma unroll
        for (int j = 0; j < 4; j++) {
#pragma unroll
            for (int r = 0; r < 4; r++) {
                float v = acc[i][j][r];
                int m = mtile + wrow * 64 + i * 16 + lgrp * 4 + r;
                int n = ntile + wcol * 64 + j * 16 + lrow;
                if (MODE == 1) {
                    outF[(size_t)m * N + n] = v;
                } else {
                    int which = n >> 10;
                    int hh = (n >> 6) & 15;
                    int d = n & 63;
                    int b = m >> 10, t = m & 1023;
                    unsigned short* dstp =
                        (which == 0) ? outQ : ((which == 1) ? outK : outV);
                    dstp[((size_t)((b << 4) + hh) * 1024 + t) * 64 + d] = f2bf(v);
                }
            }
        }
    }
}

// Flash attention, bf16 MFMA 16x16x32.  Block: 4 waves, each 16 q-rows (QBLK=64).
// KVBLK=64.  Writes attention output as [hi|lo] bf16 split rows into A3 [4096][2048].
__global__ __launch_bounds__(256) void attn_kernel(
    const unsigned short* __restrict__ Qb, const unsigned short* __restrict__ Kb,
    const unsigned short* __restrict__ Vb, const float* __restrict__ rel_bias,
    unsigned short* __restrict__ A3) {
    const int qt = blockIdx.x;  // 0..15
    const int bh = blockIdx.y;  // 0..63
    const int b = bh >> 4, h = bh & 15;
    const int tid = threadIdx.x;
    const int w = tid >> 6, lane = tid & 63;
    const int lrow = lane & 15, lgrp = lane >> 4;

    __shared__ unsigned short Ks[64][72];
    __shared__ unsigned short Vt[64][72];
    __shared__ unsigned short Ps[4][16][72];
    __shared__ float Bias_s[128];

    const unsigned short* Qp =
        Qb + ((size_t)bh * 1024 + qt * 64 + w * 16 + lrow) * 64;
    bf16x8 qa0 = *reinterpret_cast<const bf16x8*>(Qp + lgrp * 8);
    bf16x8 qa1 = *reinterpret_cast<const bf16x8*>(Qp + 32 + lgrp * 8);

    float m_run[4], l_run[4];
    f32x4 o_acc[4];
#pragma unroll
    for (int r = 0; r < 4; r++) {
        m_run[r] = -3.0e38f;
        l_run[r] = 0.f;
    }
#pragma unroll
    for (int n = 0; n < 4; n++) {
        f32x4 z = {0.f, 0.f, 0.f, 0.f};
        o_acc[n] = z;
    }

    const int i_loc = w * 16 + lgrp * 4;  // + r

    for (int kv = 0; kv < 16; ++kv) {
        const int j0 = kv * 64;
        __syncthreads();
        // K tile -> LDS (padded rows), 16B chunks
#pragma unroll
        for (int e = 0; e < 2; ++e) {
            int idx = e * 256 + tid;  // chunk id in [0,512)
            int rr = idx >> 3;
            int cc = (idx & 7) * 8;
            uint4 val = *reinterpret_cast<const uint4*>(
                Kb + ((size_t)bh * 1024 + j0 + rr) * 64 + cc);
            *reinterpret_cast<uint4*>(&Ks[rr][cc]) = val;
        }
        // V tile transposed -> LDS
#pragma unroll
        for (int e = 0; e < 16; ++e) {
            int flat = e * 256 + tid;
            int rr = flat >> 6, cc = flat & 63;
            Vt[cc][rr] = Vb[((size_t)bh * 1024 + j0 + rr) * 64 + cc];
        }
        // bias strip: rel index = (j0+jl) - (qt*64+il) + 1023 = base + (jl-il+63)
        if (tid < 128) {
            int rowi = j0 - qt * 64 + 960 + tid;
            rowi = (rowi < 2046) ? rowi : 2046;  // t=127 never read; clamp OOB
            Bias_s[tid] = rel_bias[(size_t)rowi * 16 + h];
        }
        __syncthreads();

        // S = Q K^T : lane holds S[i = i_loc + r][j = f*16 + lrow]
        f32x4 s[4];
#pragma unroll
        for (int f = 0; f < 4; ++f) {
            bf16x8 kb0 =
                *reinterpret_cast<const bf16x8*>(&Ks[f * 16 + lrow][lgrp * 8]);
            bf16x8 kb1 = *reinterpret_cast<const bf16x8*>(
                &Ks[f * 16 + lrow][32 + lgrp * 8]);
            f32x4 z = {0.f, 0.f, 0.f, 0.f};
            z = MFMA16(qa0, kb0, z);
            z = MFMA16(qa1, kb1, z);
            s[f] = z;
        }
        float p[4][4];
        float tmax[4];
#pragma unroll
        for (int r = 0; r < 4; r++) tmax[r] = -3.0e38f;
#pragma unroll
        for (int f = 0; f < 4; ++f) {
            int jl = f * 16 + lrow;
#pragma unroll
            for (int r = 0; r < 4; r++) {
                float sv = s[f][r] * 0.125f + Bias_s[jl - (i_loc + r) + 63];
                p[f][r] = sv;
                tmax[r] = fmaxf(tmax[r], sv);
            }
        }
#pragma unroll
        for (int r = 0; r < 4; r++) {
            float t = tmax[r];
            t = fmaxf(t, __shfl_xor(t, 1));
            t = fmaxf(t, __shfl_xor(t, 2));
            t = fmaxf(t, __shfl_xor(t, 4));
            t = fmaxf(t, __shfl_xor(t, 8));
            tmax[r] = t;
        }
        float corr[4];
#pragma unroll
        for (int r = 0; r < 4; r++) {
            float nm = fmaxf(m_run[r], tmax[r]);
            corr[r] = __expf(m_run[r] - nm);
            m_run[r] = nm;
            float su = 0.f;
#pragma unroll
            for (int f = 0; f < 4; ++f) {
                float pv = __expf(p[f][r] - nm);
                p[f][r] = pv;
                su += pv;
            }
            su += __shfl_xor(su, 1);
            su += __shfl_xor(su, 2);
            su += __shfl_xor(su, 4);
            su += __shfl_xor(su, 8);
            l_run[r] = l_run[r] * corr[r] + su;
        }
#pragma unroll
        for (int n = 0; n < 4; n++)
#pragma unroll
            for (int r = 0; r < 4; r++) o_acc[n][r] *= corr[r];
        // P -> per-wave LDS tile (cross-lane transpose for A-operand layout)
#pragma unroll
        for (int f = 0; f < 4; ++f)
#pragma unroll
            for (int r = 0; r < 4; r++)
                Ps[w][lgrp * 4 + r][f * 16 + lrow] = f2bf(p[f][r]);
        // O += P V  (A = P rows i, B = V[j,d] via Vt)
#pragma unroll
        for (int jc = 0; jc < 2; ++jc) {
            bf16x8 pa = *reinterpret_cast<const bf16x8*>(
                &Ps[w][lrow][jc * 32 + lgrp * 8]);
#pragma unroll
            for (int n = 0; n < 4; n++) {
                bf16x8 vb = *reinterpret_cast<const bf16x8*>(
                    &Vt[n * 16 + lrow][jc * 32 + lgrp * 8]);
                o_acc[n] = MFMA16(pa, vb, o_acc[n]);
            }
        }
    }
    // epilogue: out[b, t, h*64+d] split into [hi | lo] at A3[m][col], A3[m][1024+col]
#pragma unroll
    for (int n = 0; n < 4; n++) {
#pragma unroll
        for (int r = 0; r < 4; r++) {
            float val = o_acc[n][r] / l_run[r];
            int ia = qt * 64 + w * 16 + lgrp * 4 + r;
            size_t m = (size_t)b * 1024 + ia;
            int col = h * 64 + n * 16 + lrow;
            unsigned short hi = f2bf(val);
            float rres = val - bf2f(hi);
            A3[m * 2048 + col] = hi;
            A3[m * 2048 + 1024 + col] = f2bf(rres);
        }
    }
}

extern "C" void kernel_launch(void* const* d_in, const int* in_sizes, int n_in,
                              void* d_out, int out_size, void* d_ws,
                              size_t ws_size, hipStream_t stream) {
    const float* x = (const float*)d_in[0];
    const float* w_qkv = (const float*)d_in[1];
    const float* w_out = (const float*)d_in[2];
    const float* rel_bias = (const float*)d_in[3];
    float* out = (float*)d_out;

    char* ws = (char*)d_ws;
    size_t off = 0;
    auto alloc = [&](size_t bytes) {
        char* p = ws + off;
        off += (bytes + 255) & ~(size_t)255;
        return p;
    };
    unsigned short* A1s = (unsigned short*)alloc((size_t)4096 * 2048 * 2);
    unsigned short* W1s = (unsigned short*)alloc((size_t)3072 * 2048 * 2);
    unsigned short* Qb = (unsigned short*)alloc((size_t)64 * 1024 * 64 * 2);
    unsigned short* Kb = (unsigned short*)alloc((size_t)64 * 1024 * 64 * 2);
    unsigned short* Vb = (unsigned short*)alloc((size_t)64 * 1024 * 64 * 2);
    unsigned short* A3s = (unsigned short*)alloc((size_t)4096 * 2048 * 2);
    unsigned short* W3s = (unsigned short*)alloc((size_t)1024 * 2048 * 2);

    hipLaunchKernelGGL(prep_split_rows, dim3(2048), dim3(256), 0, stream, x, A1s,
                       4096 * 1024);
    hipLaunchKernelGGL(prep_split_wqkv, dim3(2048), dim3(256), 0, stream, w_qkv,
                       W1s);
    hipLaunchKernelGGL(prep_split_rows, dim3(1024), dim3(256), 0, stream, w_out,
                       W3s, 1024 * 1024);
    hipLaunchKernelGGL((gemm_split<0>), dim3(24, 32), dim3(256), 0, stream, A1s,
                       W1s, (float*)nullptr, Qb, Kb, Vb, 3072);
    hipLaunchKernelGGL(attn_kernel, dim3(16, 64), dim3(256), 0, stream, Qb, Kb,
                       Vb, rel_bias, A3s);
    hipLaunchKernelGGL((gemm_split<1>), dim3(8, 32), dim3(256), 0, stream, A3s,
                       W3s, out, (unsigned short*)nullptr,
                       (unsigned short*)nullptr, (unsigned short*)nullptr, 1024);
}

// Round 2
// 248.171 us; speedup vs baseline: 1.4588x; 1.4588x over previous
//
#include <hip/hip_runtime.h>
#include <hip/hip_bf16.h>

typedef short bf16x8 __attribute__((ext_vector_type(8)));
typedef float f32x4  __attribute__((ext_vector_type(4)));

typedef __attribute__((address_space(3))) void lds_t;
typedef __attribute__((address_space(1))) void gbl_t;

#define MFMA16(a,b,c) __builtin_amdgcn_mfma_f32_16x16x32_bf16((a),(b),(c),0,0,0)

__device__ __forceinline__ unsigned short f2bf(float f) {
    __hip_bfloat16 h = __float2bfloat16(f);
    return __builtin_bit_cast(unsigned short, h);
}
__device__ __forceinline__ float bf2f(unsigned short u) {
    __hip_bfloat16 h = __builtin_bit_cast(__hip_bfloat16, u);
    return __bfloat162float(h);
}

// Split f32 rows [R][1024] -> dst [R][2048] = [hi | lo] bf16.  float4 vectorized.
__global__ void prep_split_rows(const float* __restrict__ src,
                                unsigned short* __restrict__ dst, int total4) {
    for (int idx = blockIdx.x * blockDim.x + threadIdx.x; idx < total4;
         idx += gridDim.x * blockDim.x) {
        int base = idx * 4;
        int m = base >> 10, c = base & 1023;
        float4 v = *reinterpret_cast<const float4*>(src + base);
        ushort4 hi, lo;
        hi.x = f2bf(v.x); lo.x = f2bf(v.x - bf2f(hi.x));
        hi.y = f2bf(v.y); lo.y = f2bf(v.y - bf2f(hi.y));
        hi.z = f2bf(v.z); lo.z = f2bf(v.z - bf2f(hi.z));
        hi.w = f2bf(v.w); lo.w = f2bf(v.w - bf2f(hi.w));
        *reinterpret_cast<ushort4*>(dst + (size_t)m * 2048 + c) = hi;
        *reinterpret_cast<ushort4*>(dst + (size_t)m * 2048 + 1024 + c) = lo;
    }
}

// w_qkv [3072][1024] with einops row permute: output row n = which*1024 + h*64 + d
// reads source row d*48 + which*16 + h.  dst [3072][2048] = [hi | lo]
__global__ void prep_split_wqkv(const float* __restrict__ w,
                                unsigned short* __restrict__ dst) {
    for (int idx = blockIdx.x * blockDim.x + threadIdx.x; idx < 3072 * 256;
         idx += gridDim.x * blockDim.x) {
        int base = idx * 4;
        int n = base >> 10, c = base & 1023;
        int d = n & 63, which = n >> 10, h = (n >> 6) & 15;
        int srow = d * 48 + which * 16 + h;
        float4 v = *reinterpret_cast<const float4*>(w + (size_t)srow * 1024 + c);
        ushort4 hi, lo;
        hi.x = f2bf(v.x); lo.x = f2bf(v.x - bf2f(hi.x));
        hi.y = f2bf(v.y); lo.y = f2bf(v.y - bf2f(hi.y));
        hi.z = f2bf(v.z); lo.z = f2bf(v.z - bf2f(hi.z));
        hi.w = f2bf(v.w); lo.w = f2bf(v.w - bf2f(hi.w));
        *reinterpret_cast<ushort4*>(dst + (size_t)n * 2048 + c) = hi;
        *reinterpret_cast<ushort4*>(dst + (size_t)n * 2048 + 1024 + c) = lo;
    }
}

// Split GEMM, virtual K = 3072 over A=[hi|hi|lo], B=[hi|lo|hi] (each stored [rows][2048]).
// C[m,n] = sum_k A[m,k]*B[n,k].  128x128 tile, BK=32, 4 waves (2x2), wave tile 64x64.
// MODE 0: scatter bf16 into q/k/v [bh][t][64].  MODE 1: f32 out [M][N].
template <int MODE>
__global__ __launch_bounds__(256) void gemm_split(
    const unsigned short* __restrict__ A, const unsigned short* __restrict__ B,
    float* __restrict__ outF, unsigned short* __restrict__ outQ,
    unsigned short* __restrict__ outK, unsigned short* __restrict__ outV, int N) {
    __shared__ unsigned short As[128 * 32];
    __shared__ unsigned short Bs[128 * 32];
    const int tid = threadIdx.x;
    const int w = tid >> 6, lane = tid & 63;
    const int lrow = lane & 15, lgrp = lane >> 4;
    const int wrow = w >> 1, wcol = w & 1;
    const int mtile = blockIdx.y * 128, ntile = blockIdx.x * 128;

    f32x4 acc[4][4];
#pragma unroll
    for (int i = 0; i < 4; i++)
#pragma unroll
        for (int j = 0; j < 4; j++) {
            f32x4 z = {0.f, 0.f, 0.f, 0.f};
            acc[i][j] = z;
        }

    const int srow = w * 32 + (lane >> 2);  // + i*16
    const int scol = (lane & 3) * 8;

    for (int ks = 0; ks < 96; ++ks) {
        const int kb = ks * 32;
        const int ac = (kb < 1024) ? kb : kb - 1024;
        const int bc = (kb < 2048) ? kb : kb - 2048;
        __syncthreads();
#pragma unroll
        for (int i = 0; i < 2; ++i) {
            const unsigned short* ga =
                A + (size_t)(mtile + srow + i * 16) * 2048 + ac + scol;
            __builtin_amdgcn_global_load_lds((const gbl_t*)ga,
                                             (lds_t*)(As + w * 1024 + i * 512),
                                             16, 0, 0);
        }
#pragma unroll
        for (int i = 0; i < 2; ++i) {
            const unsigned short* gb =
                B + (size_t)(ntile + srow + i * 16) * 2048 + bc + scol;
            __builtin_amdgcn_global_load_lds((const gbl_t*)gb,
                                             (lds_t*)(Bs + w * 1024 + i * 512),
                                             16, 0, 0);
        }
        asm volatile("s_waitcnt vmcnt(0)" ::: "memory");
        __syncthreads();

        bf16x8 af[4], bfv[4];
#pragma unroll
        for (int i = 0; i < 4; i++)
            af[i] = *reinterpret_cast<const bf16x8*>(
                As + (wrow * 64 + i * 16 + lrow) * 32 + lgrp * 8);
#pragma unroll
        for (int j = 0; j < 4; j++)
            bfv[j] = *reinterpret_cast<const bf16x8*>(
                Bs + (wcol * 64 + j * 16 + lrow) * 32 + lgrp * 8);
#pragma unroll
        for (int i = 0; i < 4; i++)
#pragma unroll
            for (int j = 0; j < 4; j++)
                acc[i][j] = MFMA16(af[i], bfv[j], acc[i][j]);
    }

#pragma unroll
    for (int i = 0; i < 4; i++) {
#pragma unroll
        for (int j = 0; j < 4; j++) {
#pragma unroll
            for (int r = 0; r < 4; r++) {
                float v = acc[i][j][r];
                int m = mtile + wrow * 64 + i * 16 + lgrp * 4 + r;
                int n = ntile + wcol * 64 + j * 16 + lrow;
                if (MODE == 1) {
                    outF[(size_t)m * N + n] = v;
                } else {
                    int which = n >> 10;
                    int hh = (n >> 6) & 15;
                    int d = n & 63;
                    int b = m >> 10, t = m & 1023;
                    unsigned short* dstp =
                        (which == 0) ? outQ : ((which == 1) ? outK : outV);
                    dstp[((size_t)((b << 4) + hh) * 1024 + t) * 64 + d] = f2bf(v);
                }
            }
        }
    }
}

// V [bh][1024][64] -> V^T [bh][64][1024], LDS-tiled, coalesced both sides.
__global__ __launch_bounds__(256) void transpose_v(
    const unsigned short* __restrict__ Vb, unsigned short* __restrict__ Vtg) {
    __shared__ unsigned short L[64][72];
    const int tt = blockIdx.x, bh = blockIdx.y;
    const int tid = threadIdx.x;
#pragma unroll
    for (int e = 0; e < 2; ++e) {
        int chunk = e * 256 + tid;  // 512 chunks of 8 shorts
        int r = chunk >> 3, c = (chunk & 7) * 8;
        uint4 v = *reinterpret_cast<const uint4*>(
            Vb + ((size_t)bh * 1024 + tt * 64 + r) * 64 + c);
        *reinterpret_cast<uint4*>(&L[r][c]) = v;
    }
    __syncthreads();
#pragma unroll
    for (int e = 0; e < 2; ++e) {
        int chunk = e * 256 + tid;
        int d = chunk >> 3, t0 = (chunk & 7) * 8;
        unsigned short tmp[8];
#pragma unroll
        for (int u = 0; u < 8; ++u) tmp[u] = L[t0 + u][d];
        *reinterpret_cast<uint4*>(Vtg + ((size_t)bh * 64 + d) * 1024 + tt * 64 +
                                  t0) = *reinterpret_cast<const uint4*>(tmp);
    }
}

// Flash attention, bf16 MFMA 16x16x32.  4 waves x 16 q-rows (QBLK=64), KVBLK=64.
// K and V^T double-buffered in LDS via global_load_lds, XOR chunk-swizzle
// (slot c' = c ^ (row&7), applied on the GLOBAL source address since
// global_load_lds writes linearly).  One vmcnt(0)+barrier per KV tile.
__global__ __launch_bounds__(256) void attn_kernel(
    const unsigned short* __restrict__ Qb, const unsigned short* __restrict__ Kb,
    const unsigned short* __restrict__ Vtg, const float* __restrict__ rel_bias,
    unsigned short* __restrict__ A3) {
    const int qt = blockIdx.x;  // 0..15
    const int bh = blockIdx.y;  // 0..63
    const int b = bh >> 4, h = bh & 15;
    const int tid = threadIdx.x;
    const int w = tid >> 6, lane = tid & 63;
    const int lrow = lane & 15, lgrp = lane >> 4;

    __shared__ unsigned short Ks[2][64 * 64];
    __shared__ unsigned short Vs[2][64 * 64];
    __shared__ unsigned short Ps[4][16 * 64];
    __shared__ float Bias2[2][128];

    const unsigned short* Ktile = Kb + (size_t)bh * 1024 * 64;
    const unsigned short* Vtile = Vtg + (size_t)bh * 64 * 1024;

    const unsigned short* Qp =
        Qb + ((size_t)bh * 1024 + qt * 64 + w * 16 + lrow) * 64;
    bf16x8 qa0 = *reinterpret_cast<const bf16x8*>(Qp + lgrp * 8);
    bf16x8 qa1 = *reinterpret_cast<const bf16x8*>(Qp + 32 + lgrp * 8);

    // staging geometry (per wave, 2 issues each for K and V^T)
    const int sr0 = w * 16 + (lane >> 3);  // + i*8
    const int sc_lo = lane & 7;            // linear chunk slot in LDS

    float m_run[4], l_run[4];
    f32x4 o_acc[4];
#pragma unroll
    for (int r = 0; r < 4; r++) {
        m_run[r] = -3.0e38f;
        l_run[r] = 0.f;
    }
#pragma unroll
    for (int n = 0; n < 4; n++) {
        f32x4 z = {0.f, 0.f, 0.f, 0.f};
        o_acc[n] = z;
    }

    const int i_loc = w * 16 + lgrp * 4;  // + r

    // ---- prologue: stage tile 0 + bias 0 ----
    {
#pragma unroll
        for (int i = 0; i < 2; ++i) {
            int r = sr0 + i * 8;
            int c = sc_lo ^ (r & 7);  // pre-swizzled global source
            __builtin_amdgcn_global_load_lds(
                (const gbl_t*)(Ktile + (size_t)r * 64 + c * 8),
                (lds_t*)(&Ks[0][0] + w * 1024 + i * 512), 16, 0, 0);
            __builtin_amdgcn_global_load_lds(
                (const gbl_t*)(Vtile + (size_t)r * 1024 + c * 8),
                (lds_t*)(&Vs[0][0] + w * 1024 + i * 512), 16, 0, 0);
        }
        if (tid < 128) {
            int rowi = 0 - qt * 64 + 960 + tid;
            rowi = (rowi < 2046) ? rowi : 2046;
            Bias2[0][tid] = rel_bias[(size_t)rowi * 16 + h];
        }
        asm volatile("s_waitcnt vmcnt(0)" ::: "memory");
        __syncthreads();
    }

    for (int kv = 0; kv < 16; ++kv) {
        const int cur = kv & 1;
        // ---- stage next tile (overlaps with compute below) ----
        if (kv < 15) {
            const int j0n = (kv + 1) * 64;
#pragma unroll
            for (int i = 0; i < 2; ++i) {
                int r = sr0 + i * 8;
                int c = sc_lo ^ (r & 7);
                __builtin_amdgcn_global_load_lds(
                    (const gbl_t*)(Ktile + (size_t)(j0n + r) * 64 + c * 8),
                    (lds_t*)(&Ks[cur ^ 1][0] + w * 1024 + i * 512), 16, 0, 0);
                __builtin_amdgcn_global_load_lds(
                    (const gbl_t*)(Vtile + (size_t)r * 1024 + j0n + c * 8),
                    (lds_t*)(&Vs[cur ^ 1][0] + w * 1024 + i * 512), 16, 0, 0);
            }
            if (tid < 128) {
                int rowi = j0n - qt * 64 + 960 + tid;
                rowi = (rowi < 2046) ? rowi : 2046;
                Bias2[cur ^ 1][tid] = rel_bias[(size_t)rowi * 16 + h];
            }
        }

        // ---- S = Q K^T ----
        const unsigned short* kbuf = &Ks[cur][0];
        f32x4 s[4];
        __builtin_amdgcn_s_setprio(1);
#pragma unroll
        for (int f = 0; f < 4; ++f) {
            int krow = f * 16 + lrow;
            int sw0 = (lgrp ^ (lrow & 7)) * 8;
            int sw1 = ((4 | lgrp) ^ (lrow & 7)) * 8;
            bf16x8 kb0 = *reinterpret_cast<const bf16x8*>(kbuf + krow * 64 + sw0);
            bf16x8 kb1 = *reinterpret_cast<const bf16x8*>(kbuf + krow * 64 + sw1);
            f32x4 z = {0.f, 0.f, 0.f, 0.f};
            z = MFMA16(qa0, kb0, z);
            z = MFMA16(qa1, kb1, z);
            s[f] = z;
        }
        __builtin_amdgcn_s_setprio(0);

        // ---- softmax (online) ----
        float p[4][4];
        float tmax[4];
#pragma unroll
        for (int r = 0; r < 4; r++) tmax[r] = -3.0e38f;
#pragma unroll
        for (int f = 0; f < 4; ++f) {
            int jl = f * 16 + lrow;
#pragma unroll
            for (int r = 0; r < 4; r++) {
                float sv = s[f][r] * 0.125f + Bias2[cur][jl - (i_loc + r) + 63];
                p[f][r] = sv;
                tmax[r] = fmaxf(tmax[r], sv);
            }
        }
#pragma unroll
        for (int r = 0; r < 4; r++) {
            float t = tmax[r];
            t = fmaxf(t, __shfl_xor(t, 1));
            t = fmaxf(t, __shfl_xor(t, 2));
            t = fmaxf(t, __shfl_xor(t, 4));
            t = fmaxf(t, __shfl_xor(t, 8));
            tmax[r] = t;
        }
        float corr[4];
#pragma unroll
        for (int r = 0; r < 4; r++) {
            float nm = fmaxf(m_run[r], tmax[r]);
            corr[r] = __expf(m_run[r] - nm);
            m_run[r] = nm;
            float su = 0.f;
#pragma unroll
            for (int f = 0; f < 4; ++f) {
                float pv = __expf(p[f][r] - nm);
                p[f][r] = pv;
                su += pv;
            }
            su += __shfl_xor(su, 1);
            su += __shfl_xor(su, 2);
            su += __shfl_xor(su, 4);
            su += __shfl_xor(su, 8);
            l_run[r] = l_run[r] * corr[r] + su;
        }
#pragma unroll
        for (int n = 0; n < 4; n++)
#pragma unroll
            for (int r = 0; r < 4; r++) o_acc[n][r] *= corr[r];

        // ---- P -> per-wave LDS (chunk-swizzled) ----
#pragma unroll
        for (int f = 0; f < 4; ++f)
#pragma unroll
            for (int r = 0; r < 4; r++) {
                int prow = lgrp * 4 + r;
                int cs = (2 * f + (lrow >> 3)) ^ (prow & 7);
                Ps[w][prow * 64 + cs * 8 + (lrow & 7)] = f2bf(p[f][r]);
            }

        // ---- O += P V ----
        const unsigned short* vbuf = &Vs[cur][0];
        __builtin_amdgcn_s_setprio(1);
#pragma unroll
        for (int jc = 0; jc < 2; ++jc) {
            int pc = ((4 * jc + lgrp) ^ (lrow & 7)) * 8;
            bf16x8 pa =
                *reinterpret_cast<const bf16x8*>(&Ps[w][0] + lrow * 64 + pc);
#pragma unroll
            for (int n = 0; n < 4; n++) {
                int vrow = n * 16 + lrow;
                bf16x8 vb =
                    *reinterpret_cast<const bf16x8*>(vbuf + vrow * 64 + pc);
                o_acc[n] = MFMA16(pa, vb, o_acc[n]);
            }
        }
        __builtin_amdgcn_s_setprio(0);

        if (kv < 15) {
            asm volatile("s_waitcnt vmcnt(0)" ::: "memory");
            __syncthreads();
        }
    }

    // epilogue: out[b, t, h*64+d] split into [hi | lo] at A3[m][col], A3[m][1024+col]
#pragma unroll
    for (int n = 0; n < 4; n++) {
#pragma unroll
        for (int r = 0; r < 4; r++) {
            float val = o_acc[n][r] / l_run[r];
            int ia = qt * 64 + w * 16 + lgrp * 4 + r;
            size_t m = (size_t)b * 1024 + ia;
            int col = h * 64 + n * 16 + lrow;
            unsigned short hi = f2bf(val);
            float rres = val - bf2f(hi);
            A3[m * 2048 + col] = hi;
            A3[m * 2048 + 1024 + col] = f2bf(rres);
        }
    }
}

extern "C" void kernel_launch(void* const* d_in, const int* in_sizes, int n_in,
                              void* d_out, int out_size, void* d_ws,
                              size_t ws_size, hipStream_t stream) {
    const float* x = (const float*)d_in[0];
    const float* w_qkv = (const float*)d_in[1];
    const float* w_out = (const float*)d_in[2];
    const float* rel_bias = (const float*)d_in[3];
    float* out = (float*)d_out;

    char* ws = (char*)d_ws;
    size_t off = 0;
    auto alloc = [&](size_t bytes) {
        char* p = ws + off;
        off += (bytes + 255) & ~(size_t)255;
        return p;
    };
    unsigned short* A1s = (unsigned short*)alloc((size_t)4096 * 2048 * 2);
    unsigned short* W1s = (unsigned short*)alloc((size_t)3072 * 2048 * 2);
    unsigned short* Qb = (unsigned short*)alloc((size_t)64 * 1024 * 64 * 2);
    unsigned short* Kb = (unsigned short*)alloc((size_t)64 * 1024 * 64 * 2);
    unsigned short* Vb = (unsigned short*)alloc((size_t)64 * 1024 * 64 * 2);
    unsigned short* A3s = (unsigned short*)alloc((size_t)4096 * 2048 * 2);
    unsigned short* W3s = (unsigned short*)alloc((size_t)1024 * 2048 * 2);
    // V^T aliases A1s: A1s is dead after gemm_split<0>, transpose_v runs after.
    unsigned short* Vtg = A1s;

    hipLaunchKernelGGL(prep_split_rows, dim3(1024), dim3(256), 0, stream, x, A1s,
                       4096 * 256);
    hipLaunchKernelGGL(prep_split_wqkv, dim3(768), dim3(256), 0, stream, w_qkv,
                       W1s);
    hipLaunchKernelGGL(prep_split_rows, dim3(256), dim3(256), 0, stream, w_out,
                       W3s, 1024 * 256);
    hipLaunchKernelGGL((gemm_split<0>), dim3(24, 32), dim3(256), 0, stream, A1s,
                       W1s, (float*)nullptr, Qb, Kb, Vb, 3072);
    hipLaunchKernelGGL(transpose_v, dim3(16, 64), dim3(256), 0, stream, Vb, Vtg);
    hipLaunchKernelGGL(attn_kernel, dim3(16, 64), dim3(256), 0, stream, Qb, Kb,
                       Vtg, rel_bias, A3s);
    hipLaunchKernelGGL((gemm_split<1>), dim3(8, 32), dim3(256), 0, stream, A3s,
                       W3s, out, (unsigned short*)nullptr,
                       (unsigned short*)nullptr, (unsigned short*)nullptr, 1024);
}